// Round 3
// baseline (148.454 us; speedup 1.0000x reference)
//
#include <hip/hip_runtime.h>

// DiscreteHazardLoss, fused single-dispatch version.
// loss_i = -( sum_{j<t} log(1-sigmoid(x_ij)+eps) + (ev ? log(sigmoid(x_it)+eps)
//                                                     : log(1-sigmoid(x_it)+eps)) )
// Identities (eps=1e-7 negligible, |x|<~5.8 for N(0,1)):
//   log(1-sigmoid(x)) = -softplus(x);  log(sigmoid(x)) = x - softplus(x)
// => contribution for j<=t is -softplus(x_j), plus +x_t iff (j==t && ev).
// out = -(total)/B.

typedef float vfloat4 __attribute__((ext_vector_type(4)));   // native vec for nontemporal builtin

constexpr int T_BINS        = 32;
constexpr int BLOCK         = 256;
constexpr int LANES_PER_ROW = 8;                      // 8 lanes x vfloat4 = 32 cols
constexpr int ROWS_PER_ITER = BLOCK / LANES_PER_ROW;  // 32 rows/iter/block
constexpr int NBLOCKS       = 2048;

__global__ __launch_bounds__(BLOCK) void dhl_fused(
    const vfloat4* __restrict__ logits4,  // [B*8]
    const int*     __restrict__ tb,       // int32 view of time_bins
    const int*     __restrict__ ev,       // [B]
    float*         __restrict__ partials, // [nblocks]
    unsigned int*  __restrict__ counter,  // zeroed by memsetAsync each launch
    float*         __restrict__ out,
    int nrows, int rows_per_block, int nblocks, float scale)
{
    const int tid  = threadIdx.x;
    const int lane = tid & 63;

    // Inline int64-vs-int32 detection, per wave (no barrier):
    // int64 LE with values in [0,32) => all odd int32 words are 0.
    // P(false positive on int32 data) = (1/32)^64 ~ 1e-96.
    const int probe = tb[2 * lane + 1];
    const int shift = (__ballot(probe != 0) == 0ULL) ? 1 : 0;

    const int lane8 = tid & (LANES_PER_ROW - 1);
    const int rloc  = tid >> 3;
    const int j0    = lane8 * 4;
    const long long rbase = (long long)blockIdx.x * rows_per_block;

    float acc = 0.0f;
    for (int i = 0; i < rows_per_block; i += ROWS_PER_ITER) {
        long long row = rbase + i + rloc;
        if (row < nrows) {
            vfloat4 v = __builtin_nontemporal_load(&logits4[row * LANES_PER_ROW + lane8]);
            int t = tb[row << shift];
            t = min(max(t, 0), T_BINS - 1);
            const int e = ev[row];
            #pragma unroll
            for (int c = 0; c < 4; ++c) {
                float x = v[c];
                float L = __logf(1.0f + __expf(x));   // softplus(x)
                int j = j0 + c;
                if (j <= t) acc -= L;
                if (j == t && e == 1) acc += x;
            }
        }
    }

    // wave reduce
    #pragma unroll
    for (int off = 32; off > 0; off >>= 1)
        acc += __shfl_down(acc, off, 64);

    __shared__ float sw[BLOCK / 64];
    __shared__ bool  s_last;
    if (lane == 0) sw[tid >> 6] = acc;
    __syncthreads();

    if (tid == 0) {
        float s = sw[0] + sw[1] + sw[2] + sw[3];
        partials[blockIdx.x] = s;
        __threadfence();                               // release partial
        unsigned old = atomicAdd(counter, 1u);
        s_last = (old == (unsigned)(nblocks - 1));
    }
    __syncthreads();

    if (s_last) {
        __threadfence();                               // acquire others' partials
        float a = 0.0f;
        for (int i = tid; i < nblocks; i += BLOCK) a += partials[i];
        #pragma unroll
        for (int off = 32; off > 0; off >>= 1)
            a += __shfl_down(a, off, 64);
        if (lane == 0) sw[tid >> 6] = a;
        __syncthreads();
        if (tid == 0) out[0] = (sw[0] + sw[1] + sw[2] + sw[3]) * scale;
    }
}

extern "C" void kernel_launch(void* const* d_in, const int* in_sizes, int n_in,
                              void* d_out, int out_size, void* d_ws, size_t ws_size,
                              hipStream_t stream) {
    const vfloat4* logits4 = (const vfloat4*)d_in[0];
    const int*     tb      = (const int*)d_in[1];
    const int*     ev      = (const int*)d_in[2];
    float*         out     = (float*)d_out;
    const int B = in_sizes[1];   // rows

    unsigned int* counter  = (unsigned int*)d_ws;
    float*        partials = (float*)((char*)d_ws + 256);

    int rows_per_block = (B + NBLOCKS - 1) / NBLOCKS;
    rows_per_block = ((rows_per_block + ROWS_PER_ITER - 1) / ROWS_PER_ITER) * ROWS_PER_ITER;
    int nblocks = (B + rows_per_block - 1) / rows_per_block;

    (void)hipMemsetAsync(counter, 0, sizeof(unsigned int), stream);
    dhl_fused<<<nblocks, BLOCK, 0, stream>>>(logits4, tb, ev, partials, counter, out,
                                             B, rows_per_block, nblocks, -1.0f / (float)B);
}

// Round 4
// 142.410 us; speedup vs baseline: 1.0424x; 1.0424x over previous
//
#include <hip/hip_runtime.h>

// DiscreteHazardLoss, fused single-dispatch version (plain cached loads —
// nontemporal regressed 3x by forfeiting L3 residency; see round-3 post-mortem).
// loss_i = -( sum_{j<t} log(1-sigmoid(x_ij)+eps) + (ev ? log(sigmoid(x_it)+eps)
//                                                     : log(1-sigmoid(x_it)+eps)) )
// Identities (eps=1e-7 negligible, |x|<~5.8 for N(0,1)):
//   log(1-sigmoid(x)) = -softplus(x);  log(sigmoid(x)) = x - softplus(x)
// => contribution for j<=t is -softplus(x_j), plus +x_t iff (j==t && ev).
// out = -(total)/B.

constexpr int T_BINS        = 32;
constexpr int BLOCK         = 256;
constexpr int LANES_PER_ROW = 8;                      // 8 lanes x float4 = 32 cols
constexpr int ROWS_PER_ITER = BLOCK / LANES_PER_ROW;  // 32 rows/iter/block
constexpr int NBLOCKS       = 2048;

__global__ __launch_bounds__(BLOCK) void dhl_fused(
    const float4* __restrict__ logits4,   // [B*8]
    const int*    __restrict__ tb,        // int32 view of time_bins
    const int*    __restrict__ ev,        // [B]
    float*        __restrict__ partials,  // [nblocks]
    unsigned int* __restrict__ counter,   // zeroed by memsetAsync each launch
    float*        __restrict__ out,
    int nrows, int rows_per_block, int nblocks, float scale)
{
    const int tid  = threadIdx.x;
    const int lane = tid & 63;

    // Inline int64-vs-int32 detection, per wave (no barrier):
    // int64 LE with values in [0,32) => all odd int32 words are 0.
    // P(false positive on int32 data) = (1/32)^64 ~ 1e-96.
    const int probe = tb[2 * lane + 1];
    const int shift = (__ballot(probe != 0) == 0ULL) ? 1 : 0;

    const int lane8 = tid & (LANES_PER_ROW - 1);
    const int rloc  = tid >> 3;
    const int j0    = lane8 * 4;
    const long long rbase = (long long)blockIdx.x * rows_per_block;

    float acc = 0.0f;
    for (int i = 0; i < rows_per_block; i += ROWS_PER_ITER) {
        long long row = rbase + i + rloc;
        if (row < nrows) {
            float4 v = logits4[row * LANES_PER_ROW + lane8];
            int t = tb[row << shift];
            t = min(max(t, 0), T_BINS - 1);
            const int e = ev[row];
            float xs[4] = {v.x, v.y, v.z, v.w};
            #pragma unroll
            for (int c = 0; c < 4; ++c) {
                float x = xs[c];
                float L = __logf(1.0f + __expf(x));   // softplus(x)
                int j = j0 + c;
                if (j <= t) acc -= L;
                if (j == t && e == 1) acc += x;
            }
        }
    }

    // wave reduce
    #pragma unroll
    for (int off = 32; off > 0; off >>= 1)
        acc += __shfl_down(acc, off, 64);

    __shared__ float sw[BLOCK / 64];
    __shared__ bool  s_last;
    if (lane == 0) sw[tid >> 6] = acc;
    __syncthreads();

    if (tid == 0) {
        float s = sw[0] + sw[1] + sw[2] + sw[3];
        partials[blockIdx.x] = s;
        __threadfence();                               // release partial
        unsigned old = atomicAdd(counter, 1u);
        s_last = (old == (unsigned)(nblocks - 1));
    }
    __syncthreads();

    if (s_last) {
        __threadfence();                               // acquire others' partials
        float a = 0.0f;
        for (int i = tid; i < nblocks; i += BLOCK) a += partials[i];
        #pragma unroll
        for (int off = 32; off > 0; off >>= 1)
            a += __shfl_down(a, off, 64);
        if (lane == 0) sw[tid >> 6] = a;
        __syncthreads();
        if (tid == 0) out[0] = (sw[0] + sw[1] + sw[2] + sw[3]) * scale;
    }
}

extern "C" void kernel_launch(void* const* d_in, const int* in_sizes, int n_in,
                              void* d_out, int out_size, void* d_ws, size_t ws_size,
                              hipStream_t stream) {
    const float4* logits4 = (const float4*)d_in[0];
    const int*    tb      = (const int*)d_in[1];
    const int*    ev      = (const int*)d_in[2];
    float*        out     = (float*)d_out;
    const int B = in_sizes[1];   // rows

    unsigned int* counter  = (unsigned int*)d_ws;
    float*        partials = (float*)((char*)d_ws + 256);

    int rows_per_block = (B + NBLOCKS - 1) / NBLOCKS;
    rows_per_block = ((rows_per_block + ROWS_PER_ITER - 1) / ROWS_PER_ITER) * ROWS_PER_ITER;
    int nblocks = (B + rows_per_block - 1) / rows_per_block;

    (void)hipMemsetAsync(counter, 0, sizeof(unsigned int), stream);
    dhl_fused<<<nblocks, BLOCK, 0, stream>>>(logits4, tb, ev, partials, counter, out,
                                             B, rows_per_block, nblocks, -1.0f / (float)B);
}

// Round 5
// 57.834 us; speedup vs baseline: 2.5669x; 2.4624x over previous
//
#include <hip/hip_runtime.h>

// DiscreteHazardLoss — two-kernel version, NO cross-block sync.
// Round-4 post-mortem: per-block __threadfence() + device atomicAdd (last-block-
// done pattern) cost ~90us — agent-scope release fences on gfx950 write back /
// invalidate L2 per block => cache-thrash storm (hbm_gbps 911->727, dur 150us).
// Plain-store partials + separate finalize kernel is the proven-fast structure
// (round 1: 59.9us for 3 kernels); here the int64-detect kernel is folded into
// the main kernel as a fence-free wave-ballot probe => 2 dispatches total.
//
// loss_i = -( sum_{j<t} log(1-sigmoid(x_ij)+eps) + (ev ? log(sigmoid(x_it)+eps)
//                                                     : log(1-sigmoid(x_it)+eps)) )
// Identities (eps=1e-7 negligible for |x|<~5.8):
//   log(1-sigmoid(x)) = -softplus(x);  log(sigmoid(x)) = x - softplus(x)
// => per element j<=t: -softplus(x_j); plus +x_t iff (j==t && ev). out=-(sum)/B.

constexpr int T_BINS        = 32;
constexpr int BLOCK         = 256;
constexpr int LANES_PER_ROW = 8;                      // 8 lanes x float4 = 32 cols
constexpr int ROWS_PER_ITER = BLOCK / LANES_PER_ROW;  // 32 rows/iter/block
constexpr int NBLOCKS       = 2048;

__global__ __launch_bounds__(BLOCK) void dhl_main(
    const float4* __restrict__ logits4,   // [B*8]
    const int*    __restrict__ tb,        // int32 view of time_bins
    const int*    __restrict__ ev,        // [B]
    float*        __restrict__ partials,  // [nblocks]
    int nrows, int rows_per_block)
{
    const int tid  = threadIdx.x;
    const int lane = tid & 63;

    // Inline int64-vs-int32 detection, per wave (no barrier, no fence):
    // int64 LE with values in [0,32) => all odd int32 words are 0.
    // P(false positive on real int32 data) = (1/32)^64 ~ 1e-96.
    const int probe = tb[2 * lane + 1];
    const int shift = (__ballot(probe != 0) == 0ULL) ? 1 : 0;

    const int lane8 = tid & (LANES_PER_ROW - 1);
    const int rloc  = tid >> 3;
    const int j0    = lane8 * 4;
    const long long rbase = (long long)blockIdx.x * rows_per_block;

    float acc = 0.0f;
    #pragma unroll 4
    for (int i = 0; i < rows_per_block; i += ROWS_PER_ITER) {
        long long row = rbase + i + rloc;
        if (row < nrows) {
            float4 v = logits4[row * LANES_PER_ROW + lane8];
            int t = tb[row << shift];
            t = min(max(t, 0), T_BINS - 1);
            const int e = ev[row];
            float xs[4] = {v.x, v.y, v.z, v.w};
            #pragma unroll
            for (int c = 0; c < 4; ++c) {
                float x = xs[c];
                float L = __logf(1.0f + __expf(x));   // softplus(x)
                int j = j0 + c;
                if (j <= t) acc -= L;
                if (j == t && e == 1) acc += x;
            }
        }
    }

    // wave reduce
    #pragma unroll
    for (int off = 32; off > 0; off >>= 1)
        acc += __shfl_down(acc, off, 64);

    __shared__ float sw[BLOCK / 64];
    if (lane == 0) sw[tid >> 6] = acc;
    __syncthreads();
    if (tid == 0)
        partials[blockIdx.x] = sw[0] + sw[1] + sw[2] + sw[3];
}

__global__ __launch_bounds__(BLOCK) void dhl_finalize(
    const float* __restrict__ partials, int n, float* __restrict__ out, float scale)
{
    const int tid = threadIdx.x;
    float acc = 0.0f;
    for (int i = tid; i < n; i += BLOCK) acc += partials[i];
    #pragma unroll
    for (int off = 32; off > 0; off >>= 1)
        acc += __shfl_down(acc, off, 64);
    __shared__ float sw[BLOCK / 64];
    if ((tid & 63) == 0) sw[tid >> 6] = acc;
    __syncthreads();
    if (tid == 0)
        out[0] = (sw[0] + sw[1] + sw[2] + sw[3]) * scale;   // scale = -1/B
}

extern "C" void kernel_launch(void* const* d_in, const int* in_sizes, int n_in,
                              void* d_out, int out_size, void* d_ws, size_t ws_size,
                              hipStream_t stream) {
    const float4* logits4 = (const float4*)d_in[0];
    const int*    tb      = (const int*)d_in[1];
    const int*    ev      = (const int*)d_in[2];
    float*        out     = (float*)d_out;
    const int B = in_sizes[1];   // rows

    float* partials = (float*)d_ws;

    int rows_per_block = (B + NBLOCKS - 1) / NBLOCKS;
    rows_per_block = ((rows_per_block + ROWS_PER_ITER - 1) / ROWS_PER_ITER) * ROWS_PER_ITER;
    int nblocks = (B + rows_per_block - 1) / rows_per_block;

    dhl_main<<<nblocks, BLOCK, 0, stream>>>(logits4, tb, ev, partials, B, rows_per_block);
    dhl_finalize<<<1, BLOCK, 0, stream>>>(partials, nblocks, out, -1.0f / (float)B);
}

// Round 6
// 56.325 us; speedup vs baseline: 2.6357x; 1.0268x over previous
//
#include <hip/hip_runtime.h>

// DiscreteHazardLoss — two-kernel, fence-free (round-4 lesson: agent-scope
// __threadfence per block = L2 writeback storm, +90us). Round-6 change:
// guardless fast-path main kernel with explicit 4-deep batched loads to fix
// memory-level parallelism (round-5 VGPR=16 => ~1 load in flight => latency-bound
// at ~5.6 TB/s demand despite part-L3-resident inputs).
//
// loss_i = -( sum_{j<t} log(1-sigmoid(x_ij)+eps) + (ev ? log(sigmoid(x_it)+eps)
//                                                     : log(1-sigmoid(x_it)+eps)) )
// Identities (eps=1e-7 negligible for |x|<~5.8):
//   log(1-sigmoid(x)) = -softplus(x);  log(sigmoid(x)) = x - softplus(x)
// => per element j<=t: -softplus(x_j); plus +x_t iff (j==t && ev). out=-(sum)/B.

constexpr int T_BINS        = 32;
constexpr int BLOCK         = 256;
constexpr int LANES_PER_ROW = 8;                      // 8 lanes x float4 = 32 cols
constexpr int ROWS_PER_ITER = BLOCK / LANES_PER_ROW;  // 32 rows/iter/block
constexpr int NBLOCKS       = 2048;
constexpr int UNROLL        = 4;                      // 4 float4 loads in flight/lane

__device__ __forceinline__ int detect_shift(const int* tb, int lane) {
    // int64 LE with values in [0,32) => all odd int32 words are 0.
    // P(false positive on real int32 data) = (1/32)^64 ~ 1e-96.
    const int probe = tb[2 * lane + 1];
    return (__ballot(probe != 0) == 0ULL) ? 1 : 0;
}

__device__ __forceinline__ void block_reduce_store(float acc, float* dst, int tid) {
    #pragma unroll
    for (int off = 32; off > 0; off >>= 1)
        acc += __shfl_down(acc, off, 64);
    __shared__ float sw[BLOCK / 64];
    if ((tid & 63) == 0) sw[tid >> 6] = acc;
    __syncthreads();
    if (tid == 0) *dst = sw[0] + sw[1] + sw[2] + sw[3];
}

// Fast path: rows_per_block % (UNROLL*ROWS_PER_ITER) == 0, grid covers B exactly,
// all index math in 32-bit (requires B*8 < 2^31 => B <= 2^27).
__global__ __launch_bounds__(BLOCK) void dhl_main_fast(
    const float4* __restrict__ logits4,
    const int*    __restrict__ tb,
    const int*    __restrict__ ev,
    float*        __restrict__ partials,
    int rows_per_block)
{
    const int tid   = threadIdx.x;
    const int shift = detect_shift(tb, tid & 63);
    const int lane8 = tid & (LANES_PER_ROW - 1);
    const int rloc  = tid >> 3;
    const int j0    = lane8 * 4;
    const int rbase = blockIdx.x * rows_per_block;

    float acc = 0.0f;
    for (int i = 0; i < rows_per_block; i += UNROLL * ROWS_PER_ITER) {
        float4 v[UNROLL]; int t[UNROLL]; int e[UNROLL];
        #pragma unroll
        for (int u = 0; u < UNROLL; ++u) {
            const int row = rbase + i + u * ROWS_PER_ITER + rloc;
            v[u] = logits4[row * LANES_PER_ROW + lane8];
            t[u] = tb[row << shift];
            e[u] = ev[row];
        }
        #pragma unroll
        for (int u = 0; u < UNROLL; ++u) {
            const int tt = min(max(t[u], 0), T_BINS - 1);
            const float xs[4] = {v[u].x, v[u].y, v[u].z, v[u].w};
            #pragma unroll
            for (int c = 0; c < 4; ++c) {
                const float x = xs[c];
                const float L = __logf(1.0f + __expf(x));   // softplus(x)
                const int j = j0 + c;
                if (j <= tt) acc -= L;
                if (j == tt && e[u] == 1) acc += x;
            }
        }
    }
    block_reduce_store(acc, &partials[blockIdx.x], tid);
}

// Safe path: arbitrary B (64-bit rows, bounds guard).
__global__ __launch_bounds__(BLOCK) void dhl_main_safe(
    const float4* __restrict__ logits4,
    const int*    __restrict__ tb,
    const int*    __restrict__ ev,
    float*        __restrict__ partials,
    long long nrows, int rows_per_block)
{
    const int tid   = threadIdx.x;
    const int shift = detect_shift(tb, tid & 63);
    const int lane8 = tid & (LANES_PER_ROW - 1);
    const int rloc  = tid >> 3;
    const int j0    = lane8 * 4;
    const long long rbase = (long long)blockIdx.x * rows_per_block;

    float acc = 0.0f;
    for (int i = 0; i < rows_per_block; i += ROWS_PER_ITER) {
        const long long row = rbase + i + rloc;
        if (row < nrows) {
            const float4 v = logits4[row * LANES_PER_ROW + lane8];
            int t = tb[row << shift];
            t = min(max(t, 0), T_BINS - 1);
            const int e = ev[row];
            const float xs[4] = {v.x, v.y, v.z, v.w};
            #pragma unroll
            for (int c = 0; c < 4; ++c) {
                const float x = xs[c];
                const float L = __logf(1.0f + __expf(x));
                const int j = j0 + c;
                if (j <= t) acc -= L;
                if (j == t && e == 1) acc += x;
            }
        }
    }
    block_reduce_store(acc, &partials[blockIdx.x], tid);
}

__global__ __launch_bounds__(BLOCK) void dhl_finalize(
    const float* __restrict__ partials, int n, float* __restrict__ out, float scale)
{
    const int tid = threadIdx.x;
    float acc = 0.0f;
    for (int i = tid; i < n; i += BLOCK) acc += partials[i];
    #pragma unroll
    for (int off = 32; off > 0; off >>= 1)
        acc += __shfl_down(acc, off, 64);
    __shared__ float sw[BLOCK / 64];
    if ((tid & 63) == 0) sw[tid >> 6] = acc;
    __syncthreads();
    if (tid == 0)
        out[0] = (sw[0] + sw[1] + sw[2] + sw[3]) * scale;   // scale = -1/B
}

extern "C" void kernel_launch(void* const* d_in, const int* in_sizes, int n_in,
                              void* d_out, int out_size, void* d_ws, size_t ws_size,
                              hipStream_t stream) {
    const float4* logits4 = (const float4*)d_in[0];
    const int*    tb      = (const int*)d_in[1];
    const int*    ev      = (const int*)d_in[2];
    float*        out     = (float*)d_out;
    const int B = in_sizes[1];   // rows

    float* partials = (float*)d_ws;

    int rows_per_block = (B + NBLOCKS - 1) / NBLOCKS;
    const int step = UNROLL * ROWS_PER_ITER;
    rows_per_block = ((rows_per_block + step - 1) / step) * step;
    const int nblocks = (B + rows_per_block - 1) / rows_per_block;

    const bool fast = (B % rows_per_block == 0) && (B <= (1 << 27));
    if (fast) {
        dhl_main_fast<<<nblocks, BLOCK, 0, stream>>>(logits4, tb, ev, partials, rows_per_block);
    } else {
        dhl_main_safe<<<nblocks, BLOCK, 0, stream>>>(logits4, tb, ev, partials,
                                                     (long long)B, rows_per_block);
    }
    dhl_finalize<<<1, BLOCK, 0, stream>>>(partials, nblocks, out, -1.0f / (float)B);
}

// Round 7
// 54.036 us; speedup vs baseline: 2.7473x; 1.0424x over previous
//
#include <hip/hip_runtime.h>

// DiscreteHazardLoss — two-kernel, fence-free.
// R4 lesson: per-block __threadfence + device atomicAdd = L2 writeback storm (+90us).
// R6 lesson: FETCH_SIZE(139MB) << touched(285MB) => half L3-resident; kernel is
// latency/MLP-bound (~5.7 TB/s demand). R7: explicit double-buffered register
// pipeline (named A/B batches, compile-time indices only) to double bytes in
// flight per wave and overlap loads with the exp/log chain.
//
// loss_i = -( sum_{j<t} log(1-sigmoid(x_ij)+eps) + (ev ? log(sigmoid(x_it)+eps)
//                                                     : log(1-sigmoid(x_it)+eps)) )
// Identities (eps=1e-7 negligible for |x|<~5.8):
//   log(1-sigmoid(x)) = -softplus(x);  log(sigmoid(x)) = x - softplus(x)
// => per element j<=t: -softplus(x_j); plus +x_t iff (j==t && ev). out=-(sum)/B.

constexpr int T_BINS        = 32;
constexpr int BLOCK         = 256;
constexpr int LANES_PER_ROW = 8;                      // 8 lanes x float4 = 32 cols
constexpr int ROWS_PER_ITER = BLOCK / LANES_PER_ROW;  // 32 rows/iter/block
constexpr int NBLOCKS       = 2048;
constexpr int U             = 4;                      // rows-groups per batch
constexpr int STEP          = U * ROWS_PER_ITER;      // 128 rows per batch
constexpr int PIPE          = 2 * STEP;               // 256 rows per pipelined iter

__device__ __forceinline__ int detect_shift(const int* tb, int lane) {
    // int64 LE with values in [0,32) => all odd int32 words are 0.
    // P(false positive on real int32 data) = (1/32)^64 ~ 1e-96.
    const int probe = tb[2 * lane + 1];
    return (__ballot(probe != 0) == 0ULL) ? 1 : 0;
}

__device__ __forceinline__ void block_reduce_store(float acc, float* dst, int tid) {
    #pragma unroll
    for (int off = 32; off > 0; off >>= 1)
        acc += __shfl_down(acc, off, 64);
    __shared__ float sw[BLOCK / 64];
    if ((tid & 63) == 0) sw[tid >> 6] = acc;
    __syncthreads();
    if (tid == 0) *dst = sw[0] + sw[1] + sw[2] + sw[3];
}

// Fast path: rows_per_block % PIPE == 0, grid covers B exactly, 32-bit indexing.
__global__ __launch_bounds__(BLOCK) void dhl_main_fast(
    const float4* __restrict__ logits4,
    const int*    __restrict__ tb,
    const int*    __restrict__ ev,
    float*        __restrict__ partials,
    int rows_per_block)
{
    const int tid   = threadIdx.x;
    const int shift = detect_shift(tb, tid & 63);
    const int lane8 = tid & (LANES_PER_ROW - 1);
    const int rloc  = tid >> 3;
    const int j0    = lane8 * 4;
    const int rbase = blockIdx.x * rows_per_block;

    float4 vA[U]; int tA[U]; int eA[U];
    float4 vB[U]; int tB[U]; int eB[U];
    float acc = 0.0f;

#define DHL_LOAD(V, T, E, base)                                                 \
    _Pragma("unroll")                                                           \
    for (int u = 0; u < U; ++u) {                                               \
        const int row_ = (base) + u * ROWS_PER_ITER + rloc;                     \
        V[u] = logits4[row_ * LANES_PER_ROW + lane8];                           \
        T[u] = tb[row_ << shift];                                               \
        E[u] = ev[row_];                                                        \
    }

#define DHL_COMPUTE(V, T, E)                                                    \
    _Pragma("unroll")                                                           \
    for (int u = 0; u < U; ++u) {                                               \
        const int tt_ = min(max(T[u], 0), T_BINS - 1);                          \
        const float xs_[4] = {V[u].x, V[u].y, V[u].z, V[u].w};                  \
        _Pragma("unroll")                                                       \
        for (int c = 0; c < 4; ++c) {                                           \
            const float x_ = xs_[c];                                            \
            const float L_ = __logf(1.0f + __expf(x_));                         \
            const int j_ = j0 + c;                                              \
            if (j_ <= tt_) acc -= L_;                                           \
            if (j_ == tt_ && E[u] == 1) acc += x_;                              \
        }                                                                       \
    }

    DHL_LOAD(vA, tA, eA, rbase)
    for (int i = 0; i < rows_per_block; i += PIPE) {
        DHL_LOAD(vB, tB, eB, rbase + i + STEP)
        DHL_COMPUTE(vA, tA, eA)
        if (i + PIPE < rows_per_block) {
            DHL_LOAD(vA, tA, eA, rbase + i + PIPE)
        }
        DHL_COMPUTE(vB, tB, eB)
    }
#undef DHL_LOAD
#undef DHL_COMPUTE

    block_reduce_store(acc, &partials[blockIdx.x], tid);
}

// Safe path: arbitrary B (64-bit rows, bounds guard).
__global__ __launch_bounds__(BLOCK) void dhl_main_safe(
    const float4* __restrict__ logits4,
    const int*    __restrict__ tb,
    const int*    __restrict__ ev,
    float*        __restrict__ partials,
    long long nrows, int rows_per_block)
{
    const int tid   = threadIdx.x;
    const int shift = detect_shift(tb, tid & 63);
    const int lane8 = tid & (LANES_PER_ROW - 1);
    const int rloc  = tid >> 3;
    const int j0    = lane8 * 4;
    const long long rbase = (long long)blockIdx.x * rows_per_block;

    float acc = 0.0f;
    for (int i = 0; i < rows_per_block; i += ROWS_PER_ITER) {
        const long long row = rbase + i + rloc;
        if (row < nrows) {
            const float4 v = logits4[row * LANES_PER_ROW + lane8];
            int t = tb[row << shift];
            t = min(max(t, 0), T_BINS - 1);
            const int e = ev[row];
            const float xs[4] = {v.x, v.y, v.z, v.w};
            #pragma unroll
            for (int c = 0; c < 4; ++c) {
                const float x = xs[c];
                const float L = __logf(1.0f + __expf(x));
                const int j = j0 + c;
                if (j <= t) acc -= L;
                if (j == t && e == 1) acc += x;
            }
        }
    }
    block_reduce_store(acc, &partials[blockIdx.x], tid);
}

__global__ __launch_bounds__(BLOCK) void dhl_finalize(
    const float* __restrict__ partials, int n, float* __restrict__ out, float scale)
{
    const int tid = threadIdx.x;
    float acc = 0.0f;
    for (int i = tid; i < n; i += BLOCK) acc += partials[i];
    #pragma unroll
    for (int off = 32; off > 0; off >>= 1)
        acc += __shfl_down(acc, off, 64);
    __shared__ float sw[BLOCK / 64];
    if ((tid & 63) == 0) sw[tid >> 6] = acc;
    __syncthreads();
    if (tid == 0)
        out[0] = (sw[0] + sw[1] + sw[2] + sw[3]) * scale;   // scale = -1/B
}

extern "C" void kernel_launch(void* const* d_in, const int* in_sizes, int n_in,
                              void* d_out, int out_size, void* d_ws, size_t ws_size,
                              hipStream_t stream) {
    const float4* logits4 = (const float4*)d_in[0];
    const int*    tb      = (const int*)d_in[1];
    const int*    ev      = (const int*)d_in[2];
    float*        out     = (float*)d_out;
    const int B = in_sizes[1];   // rows

    float* partials = (float*)d_ws;

    int rows_per_block = (B + NBLOCKS - 1) / NBLOCKS;
    rows_per_block = ((rows_per_block + PIPE - 1) / PIPE) * PIPE;
    const int nblocks = (B + rows_per_block - 1) / rows_per_block;

    const bool fast = (B % rows_per_block == 0) && (B <= (1 << 27));
    if (fast) {
        dhl_main_fast<<<nblocks, BLOCK, 0, stream>>>(logits4, tb, ev, partials, rows_per_block);
    } else {
        dhl_main_safe<<<nblocks, BLOCK, 0, stream>>>(logits4, tb, ev, partials,
                                                     (long long)B, rows_per_block);
    }
    dhl_finalize<<<1, BLOCK, 0, stream>>>(partials, nblocks, out, -1.0f / (float)B);
}